// Round 4
// baseline (444.809 us; speedup 1.0000x reference)
//
#include <hip/hip_runtime.h>
#include <cstdint>
#include <cstddef>

typedef unsigned int u32;
typedef unsigned short u16;
typedef __bf16 bf16x8 __attribute__((ext_vector_type(8)));
typedef float f32x4 __attribute__((ext_vector_type(4)));
typedef u16 u16x8 __attribute__((ext_vector_type(8)));

static constexpr int T_TOK = 4096;
static constexpr int HID   = 2048;
static constexpr int INTER = 1024;
static constexpr int NEXP  = 8;
static constexpr int TOPK  = 2;
static constexpr int SLOT_CAP = 9216;          // 8192 real + per-expert 128-align pad
static constexpr int NTILE_M = SLOT_CAP / 128; // 72 m-tiles

static constexpr int META_TOK = 32;
static constexpr int META_SLOTOF = 32 + SLOT_CAP;

__device__ __forceinline__ u16 f2bf(float f) {
  u32 u = __builtin_bit_cast(u32, f);
  u32 r = (u + 0x7fffu + ((u >> 16) & 1u)) >> 16;
  return (u16)r;
}
__device__ __forceinline__ float bf2f(u16 h) {
  return __builtin_bit_cast(float, (u32)h << 16);
}

// ---------------- router ----------------
__global__ void router_count(const int* __restrict__ eidx, int* __restrict__ meta) {
  __shared__ int cnt[NEXP];
  const int tid = threadIdx.x;
  if (tid < NEXP) cnt[tid] = 0;
  __syncthreads();
  for (int i = tid; i < T_TOK * TOPK; i += 256) atomicAdd(&cnt[eidx[i]], 1);
  __syncthreads();
  if (tid == 0) {
    int off = 0;
    for (int e = 0; e < NEXP; ++e) {
      int c = cnt[e];
      meta[e] = c;
      meta[8 + e] = off;
      meta[17 + e] = off;
      off += (c + 127) & ~127;
    }
    meta[16] = off;
  }
}

__global__ void toklist_init(int* __restrict__ meta) {
  const int i = blockIdx.x * 256 + threadIdx.x;
  if (i < SLOT_CAP) meta[META_TOK + i] = 0;   // pad rows use token 0
}

__global__ void router_assign(const int* __restrict__ eidx, int* __restrict__ meta) {
  const int t = blockIdx.x * 256 + threadIdx.x;
  if (t >= T_TOK) return;
  int* cursors = meta + 17;
  int* toklist = meta + META_TOK;
  int* slot_of = meta + META_SLOTOF;
  for (int k = 0; k < TOPK; ++k) {
    const int e = eidx[t * TOPK + k];
    const int pos = atomicAdd(&cursors[e], 1);
    toklist[pos] = t;
    slot_of[t * TOPK + k] = pos;
  }
}

// ---------------- dequant / cast ----------------
template <int CPR>
__global__ void dequant_k(const int* __restrict__ p, const float* __restrict__ s,
                          u16* __restrict__ w) {
  const int gid = blockIdx.x * 256 + threadIdx.x;
  const int row = gid / CPR;
  const int cid = gid % CPR;
  const int4 pk = *(const int4*)(p + (size_t)gid * 4);
  const float sc = s[(size_t)row * (CPR / 4) + (cid >> 2)];
  int v[4] = {pk.x, pk.y, pk.z, pk.w};
  u16x8 o;
#pragma unroll
  for (int b = 0; b < 4; ++b) {
    o[2 * b]     = f2bf((float)((v[b] & 15) - 8) * sc);
    o[2 * b + 1] = f2bf((float)(((v[b] >> 4) & 15) - 8) * sc);
  }
  *(u16x8*)(w + (size_t)gid * 8) = o;
}

__global__ void cast_x_k(const float* __restrict__ x, u16* __restrict__ xb) {
  const int i = (blockIdx.x * 256 + threadIdx.x) * 8;
  const float4 a = *(const float4*)(x + i);
  const float4 b = *(const float4*)(x + i + 4);
  u16x8 o;
  o[0] = f2bf(a.x); o[1] = f2bf(a.y); o[2] = f2bf(a.z); o[3] = f2bf(a.w);
  o[4] = f2bf(b.x); o[5] = f2bf(b.y); o[6] = f2bf(b.z); o[7] = f2bf(b.w);
  *(u16x8*)(xb + i) = o;
}

// ---------------- grouped GEMM: A in registers, B-only LDS ring ----------------
// C[slot, n] = sum_k A[row(slot), k] * B[n, k]  (B is K-major / B^T)
// BM=128 x BN=256, BK=64, 8 waves (2M x 4N), wave-tile 64x64.
// R3 post-mortem: 176KB LDS traffic per K-tile (A+B reads + stage writes) was
// the bound (~1570cy vs 310cy MFMA). Fix: A fragments load global->VGPR
// (double-buffered, prefetch 1 tile; A rows are wave-private and L2-hot),
// LDS holds only B in a 4-deep ring (4x32KB). One barrier + counted vmcnt(12)
// per tile: outstanding = B(kt+1) 4 + A(kt) 8; oldest-retire vmcnt certifies
// B(kt) landed without draining the pipe. Hand-unrolled x4 so all ring/parity
// indices are compile-time (rule #20).
template <int KT, bool GATHER>
__global__ __launch_bounds__(512, 2) void gemm_ar(const u16* __restrict__ A,
                                                  const u16* __restrict__ B,
                                                  u16* __restrict__ C,
                                                  const int* __restrict__ meta) {
  static constexpr int NT = KT / 64;   // 32 or 16, both divisible by 4

  const int bid = blockIdx.x;
  const int xcd = bid & 7, q = bid >> 3;
  const int mt = xcd * 9 + (q >> 3);
  const int nt = q & 7;
  const int slot0 = mt * 128;
  if (slot0 >= meta[16]) return;
  int e = 0;
#pragma unroll
  for (int i = 1; i < NEXP; ++i) e += (slot0 >= meta[8 + i]);
  const int n0 = nt * 256;
  const int tid = threadIdx.x;

  __shared__ u16 lds[4 * 16384];   // 4 ring buffers x 32KB (B panel 256x64)
  char* ldsB = (char*)lds;

  const u16* Be = B + (size_t)e * 2048 * KT;
  const int* toklist = meta + META_TOK;

  // B staging sources: dest linear byte L -> subtile S=L>>10, o swizzled by
  // o^=((o>>8)&3)<<4; row r=(S>>1)*16+(o>>6), col byte cb=(S&1)*64+(o&63).
  const u16* bsrc[4];
#pragma unroll
  for (int j = 0; j < 4; ++j) {
    const int L = j * 8192 + tid * 16;
    const int S = L >> 10;
    int o = L & 1023;
    o ^= ((o >> 8) & 3) << 4;
    const int r = (S >> 1) * 16 + (o >> 6);
    const int cb = (S & 1) * 64 + (o & 63);
    bsrc[j] = Be + (size_t)(n0 + r) * KT + (cb >> 1);
  }

  const int lane = tid & 63;
  const int wid = tid >> 6;
  const int wm = (wid >> 2) * 64;   // 2 M-groups
  const int wn = (wid & 3) * 64;    // 4 N-groups
  const int fr = lane & 15;
  const int qq = lane >> 4;
  const int swz = (qq * 16) ^ (((fr >> 2) & 3) << 4);

  // B fragment LDS byte offsets (within one ring buffer)
  int boffb[4][2];
#pragma unroll
  for (int n = 0; n < 4; ++n)
#pragma unroll
    for (int ks = 0; ks < 2; ++ks)
      boffb[n][ks] = ((wn >> 4) + n) * 2048 + ks * 1024 + fr * 64 + swz;

  // A row base pointers (per lane; rows are wave-private)
  const u16* abase[4];
#pragma unroll
  for (int m = 0; m < 4; ++m) {
    const int slot = slot0 + wm + m * 16 + fr;
    const int arow = GATHER ? toklist[slot] : slot;
    abase[m] = A + (size_t)arow * KT + qq * 8;
  }

  f32x4 acc[4][4];
#pragma unroll
  for (int m = 0; m < 4; ++m)
#pragma unroll
    for (int n = 0; n < 4; ++n) acc[m][n] = (f32x4)0.0f;

  bf16x8 arA[4][2], arB[4][2];

#define STAGEB(kt_, b_)                                                             \
  do {                                                                              \
    char* dB_ = ldsB + (b_) * 32768;                                                \
    _Pragma("unroll") for (int j = 0; j < 4; ++j)                                   \
        __builtin_amdgcn_global_load_lds(                                           \
            (const __attribute__((address_space(1))) void*)(bsrc[j] + (kt_) * 64),  \
            (__attribute__((address_space(3))) void*)(dB_ + j * 8192 + tid * 16),   \
            16, 0, 0);                                                              \
  } while (0)

#define LOADA(kt_, AR_)                                                             \
  do {                                                                              \
    const int kc_ = ((kt_) < NT ? (kt_) : NT - 1) * 64;                             \
    _Pragma("unroll") for (int m = 0; m < 4; ++m)                                   \
        _Pragma("unroll") for (int ks = 0; ks < 2; ++ks)                            \
            AR_[m][ks] = *(const bf16x8*)(abase[m] + kc_ + ks * 32);                \
  } while (0)

#define TILE(kt_, C_, ARc_, ARn_)                                                   \
  do {                                                                              \
    asm volatile("s_waitcnt vmcnt(12)" ::: "memory");                               \
    __builtin_amdgcn_s_barrier();                                                   \
    __builtin_amdgcn_sched_barrier(0);                                              \
    if ((kt_) + 2 < NT) STAGEB((kt_) + 2, ((C_) + 2) & 3);                          \
    LOADA((kt_) + 1, ARn_);                                                         \
    const char* bufc_ = ldsB + (C_) * 32768;                                        \
    bf16x8 bfr_[4][2];                                                              \
    _Pragma("unroll") for (int n = 0; n < 4; ++n)                                   \
        _Pragma("unroll") for (int ks = 0; ks < 2; ++ks)                            \
            bfr_[n][ks] = *(const bf16x8*)(bufc_ + boffb[n][ks]);                   \
    _Pragma("unroll") for (int m = 0; m < 4; ++m)                                   \
        _Pragma("unroll") for (int n = 0; n < 4; ++n)                               \
            _Pragma("unroll") for (int ks = 0; ks < 2; ++ks)                        \
                acc[m][n] = __builtin_amdgcn_mfma_f32_16x16x32_bf16(                \
                    ARc_[m][ks], bfr_[n][ks], acc[m][n], 0, 0, 0);                  \
  } while (0)

  // prologue: 2 B-tiles staged (8 loads), A tile0 in regs (8 loads)
  STAGEB(0, 0);
  STAGEB(1, 1);
  LOADA(0, arA);

  for (int k4 = 0; k4 < NT; k4 += 4) {
    TILE(k4 + 0, 0, arA, arB);
    TILE(k4 + 1, 1, arB, arA);
    TILE(k4 + 2, 2, arA, arB);
    TILE(k4 + 3, 3, arB, arA);
  }
#undef STAGEB
#undef LOADA
#undef TILE

  // epilogue: C/D layout col=lane&15, row=(lane>>4)*4+j
  const int cr = qq * 4;
#pragma unroll
  for (int m = 0; m < 4; ++m)
#pragma unroll
    for (int n = 0; n < 4; ++n)
#pragma unroll
      for (int j = 0; j < 4; ++j) {
        const int row = slot0 + wm + m * 16 + cr + j;
        const int col = n0 + wn + n * 16 + fr;
        C[(size_t)row * 2048 + col] = f2bf(acc[m][n][j]);
      }
}

// ---------------- silu ----------------
__global__ void silu_k(const u16* __restrict__ y13, u16* __restrict__ h,
                       const int* __restrict__ meta) {
  const int idx = blockIdx.x * 256 + threadIdx.x;
  const int slot = idx >> 7;
  if (slot >= meta[16]) return;
  const int pos = (idx & 127) * 8;
  u16x8 g8 = *(const u16x8*)(y13 + (size_t)slot * 2048 + pos);
  u16x8 u8 = *(const u16x8*)(y13 + (size_t)slot * 2048 + 1024 + pos);
  u16x8 o;
#pragma unroll
  for (int j = 0; j < 8; ++j) {
    const float g = bf2f(g8[j]);
    const float u = bf2f(u8[j]);
    const float sg = g / (1.0f + __expf(-g));
    o[j] = f2bf(sg * u);
  }
  *(u16x8*)(h + (size_t)slot * 1024 + pos) = o;
}

// ---------------- combine ----------------
__global__ void combine_k(const u16* __restrict__ yp, const float* __restrict__ ew,
                          const int* __restrict__ meta, float* __restrict__ out) {
  const int idx = blockIdx.x * 256 + threadIdx.x;
  const int t = idx >> 8;
  const int pos = (idx & 255) * 8;
  const int* slot_of = meta + META_SLOTOF;
  const int s0 = slot_of[t * 2];
  const int s1 = slot_of[t * 2 + 1];
  const float w0 = ew[t * 2];
  const float w1 = ew[t * 2 + 1];
  const u16x8 v0 = *(const u16x8*)(yp + (size_t)s0 * 2048 + pos);
  const u16x8 v1 = *(const u16x8*)(yp + (size_t)s1 * 2048 + pos);
  float* dst = out + (size_t)t * 2048 + pos;
  float4 o0, o1;
  o0.x = w0 * bf2f(v0[0]) + w1 * bf2f(v1[0]);
  o0.y = w0 * bf2f(v0[1]) + w1 * bf2f(v1[1]);
  o0.z = w0 * bf2f(v0[2]) + w1 * bf2f(v1[2]);
  o0.w = w0 * bf2f(v0[3]) + w1 * bf2f(v1[3]);
  o1.x = w0 * bf2f(v0[4]) + w1 * bf2f(v1[4]);
  o1.y = w0 * bf2f(v0[5]) + w1 * bf2f(v1[5]);
  o1.z = w0 * bf2f(v0[6]) + w1 * bf2f(v1[6]);
  o1.w = w0 * bf2f(v0[7]) + w1 * bf2f(v1[7]);
  *(float4*)dst = o0;
  *(float4*)(dst + 4) = o1;
}

// ---------------- launch ----------------
extern "C" void kernel_launch(void* const* d_in, const int* in_sizes, int n_in,
                              void* d_out, int out_size, void* d_ws, size_t ws_size,
                              hipStream_t stream) {
  const float* x    = (const float*)d_in[0];
  const int*   w1   = (const int*)d_in[1];
  const float* w1s  = (const float*)d_in[2];
  const int*   w2   = (const int*)d_in[3];
  const float* w2s  = (const float*)d_in[4];
  const float* ew   = (const float*)d_in[5];
  const int*   eidx = (const int*)d_in[6];
  float* out = (float*)d_out;

  char* ws = (char*)d_ws;
  const size_t OFF_W1B  = 0;           // 8*2048*2048*2  = 67,108,864
  const size_t OFF_W2B  = 67108864;    // 8*2048*1024*2  = 33,554,432
  const size_t OFF_XB   = 100663296;   // 4096*2048*2    = 16,777,216
  const size_t OFF_Y13  = 117440512;   // 9216*2048*2    = 37,748,736 (also yp, reused)
  const size_t OFF_H    = 155189248;   // 9216*1024*2    = 18,874,368
  const size_t OFF_META = 174063616;   // 17440*4        = 69,760
  const size_t NEED     = 174133376;
  if (ws_size < NEED) return;

  u16* W1b  = (u16*)(ws + OFF_W1B);
  u16* W2b  = (u16*)(ws + OFF_W2B);
  u16* xb   = (u16*)(ws + OFF_XB);
  u16* y13  = (u16*)(ws + OFF_Y13);
  u16* hbuf = (u16*)(ws + OFF_H);
  int* meta = (int*)(ws + OFF_META);

  router_count<<<1, 256, 0, stream>>>(eidx, meta);
  toklist_init<<<SLOT_CAP / 256, 256, 0, stream>>>(meta);
  router_assign<<<T_TOK / 256, 256, 0, stream>>>(eidx, meta);

  cast_x_k<<<(T_TOK * HID) / (256 * 8), 256, 0, stream>>>(x, xb);
  dequant_k<256><<<16384 * 256 / 256, 256, 0, stream>>>(w1, w1s, W1b);
  dequant_k<128><<<16384 * 128 / 256, 256, 0, stream>>>(w2, w2s, W2b);

  // GEMM1: y13[slot, 0..2048) = x[tok] . W1^T  (K=2048, gather); 72x8=576 blocks
  gemm_ar<2048, true><<<NTILE_M * 8, 512, 0, stream>>>(xb, W1b, y13, meta);
  silu_k<<<SLOT_CAP * (INTER / 8) / 256, 256, 0, stream>>>(y13, hbuf, meta);
  // GEMM2: yp[slot, 0..2048) = h[slot] . W2^T  (K=1024, contiguous); yp aliases y13
  gemm_ar<1024, false><<<NTILE_M * 8, 512, 0, stream>>>(hbuf, W2b, y13, meta);

  combine_k<<<(T_TOK * HID) / (256 * 8), 256, 0, stream>>>(y13, ew, meta, out);
}

// Round 5
// 278.945 us; speedup vs baseline: 1.5946x; 1.5946x over previous
//
#include <hip/hip_runtime.h>
#include <cstdint>
#include <cstddef>

typedef unsigned int u32;
typedef unsigned short u16;
typedef __bf16 bf16x8 __attribute__((ext_vector_type(8)));
typedef float f32x4 __attribute__((ext_vector_type(4)));
typedef u16 u16x8 __attribute__((ext_vector_type(8)));

static constexpr int T_TOK = 4096;
static constexpr int HID   = 2048;
static constexpr int INTER = 1024;
static constexpr int NEXP  = 8;
static constexpr int TOPK  = 2;
static constexpr int SLOT_CAP = 10240;          // 8192 real + per-expert 256-align pad
static constexpr int NT_M = SLOT_CAP / 256;     // 40 m-tiles

static constexpr int META_TOK = 32;
static constexpr int META_SLOTOF = 32 + SLOT_CAP;

__device__ __forceinline__ u16 f2bf(float f) {
  u32 u = __builtin_bit_cast(u32, f);
  u32 r = (u + 0x7fffu + ((u >> 16) & 1u)) >> 16;
  return (u16)r;
}
__device__ __forceinline__ float bf2f(u16 h) {
  return __builtin_bit_cast(float, (u32)h << 16);
}

// ---------------- router ----------------
__global__ void router_count(const int* __restrict__ eidx, int* __restrict__ meta) {
  __shared__ int cnt[NEXP];
  const int tid = threadIdx.x;
  if (tid < NEXP) cnt[tid] = 0;
  __syncthreads();
  for (int i = tid; i < T_TOK * TOPK; i += 256) atomicAdd(&cnt[eidx[i]], 1);
  __syncthreads();
  if (tid == 0) {
    int off = 0;
    for (int e = 0; e < NEXP; ++e) {
      int c = cnt[e];
      meta[e] = c;
      meta[8 + e] = off;
      meta[17 + e] = off;
      off += (c + 255) & ~255;      // 256-aligned regions (BM=256)
    }
    meta[16] = off;
  }
}

__global__ void toklist_init(int* __restrict__ meta) {
  const int i = blockIdx.x * 256 + threadIdx.x;
  if (i < SLOT_CAP) meta[META_TOK + i] = 0;   // pad rows use token 0
}

__global__ void router_assign(const int* __restrict__ eidx, int* __restrict__ meta) {
  const int t = blockIdx.x * 256 + threadIdx.x;
  if (t >= T_TOK) return;
  int* cursors = meta + 17;
  int* toklist = meta + META_TOK;
  int* slot_of = meta + META_SLOTOF;
  for (int k = 0; k < TOPK; ++k) {
    const int e = eidx[t * TOPK + k];
    const int pos = atomicAdd(&cursors[e], 1);
    toklist[pos] = t;
    slot_of[t * TOPK + k] = pos;
  }
}

// ---------------- dequant / cast ----------------
template <int CPR>
__global__ void dequant_k(const int* __restrict__ p, const float* __restrict__ s,
                          u16* __restrict__ w) {
  const int gid = blockIdx.x * 256 + threadIdx.x;
  const int row = gid / CPR;
  const int cid = gid % CPR;
  const int4 pk = *(const int4*)(p + (size_t)gid * 4);
  const float sc = s[(size_t)row * (CPR / 4) + (cid >> 2)];
  int v[4] = {pk.x, pk.y, pk.z, pk.w};
  u16x8 o;
#pragma unroll
  for (int b = 0; b < 4; ++b) {
    o[2 * b]     = f2bf((float)((v[b] & 15) - 8) * sc);
    o[2 * b + 1] = f2bf((float)(((v[b] >> 4) & 15) - 8) * sc);
  }
  *(u16x8*)(w + (size_t)gid * 8) = o;
}

__global__ void cast_x_k(const float* __restrict__ x, u16* __restrict__ xb) {
  const int i = (blockIdx.x * 256 + threadIdx.x) * 8;
  const float4 a = *(const float4*)(x + i);
  const float4 b = *(const float4*)(x + i + 4);
  u16x8 o;
  o[0] = f2bf(a.x); o[1] = f2bf(a.y); o[2] = f2bf(a.z); o[3] = f2bf(a.w);
  o[4] = f2bf(b.x); o[5] = f2bf(b.y); o[6] = f2bf(b.z); o[7] = f2bf(b.w);
  *(u16x8*)(xb + i) = o;
}

// ---------------- grouped GEMM, 256x256 tile (m201 geometry) ----------------
// C[slot, n] = sum_k A[row(slot), k] * B[n, k]   (B is K-major / B^T)
// BM=BN=256, BK=64, 8 waves (2M x 4N), wave tile 128x64 -> per wave per
// K-tile: 24 ds_read_b128 (288cy) vs 64 MFMA (310cy): MFMA-bound (R3/R4
// post-mortem: 64x64 wave tile was LDS-issue-bound; per-lane A loads were
// TA-pipe-bound). Dbuf LDS 2x(A 32K + B 32K)=128KB. Stage kt+1 right after
// tile kt's top barrier so the vmcnt(0) at kt+1's top fires ~600cy after
// issue (drain is latency-covered; m97's stall was same-tile issue+drain).
// LDS layout: packed 1KB 16x32-bf16 subtiles, XOR swizzle o^=((o>>8)&3)<<4
// (verified ~2-way residual in R4); global source pre-swizzled (m173).
// GUP=true (GEMM1): B rows map to W1 gate[nt*128+g*32+j] / up[1024+...], and
// the epilogue computes h = silu(gate)*up in-register (acc[m][n] pairs with
// acc[m][n+2]) writing h directly -> silu kernel + y13 buffer eliminated.
template <int KT, bool GATHER, bool GUP>
__global__ __launch_bounds__(512, 2) void gemm256(const u16* __restrict__ A,
                                                  const u16* __restrict__ B,
                                                  u16* __restrict__ Cout,
                                                  const int* __restrict__ meta) {
  static constexpr int NT = KT / 64;
  static constexpr int OSTR = GUP ? INTER : HID;

  // bid = nt*40 + mt  ->  XCD = bid%8 = mt%8: same-mt blocks (shared gathered
  // A rows) land on one XCD's L2.
  const int bid = blockIdx.x;
  const int mt = bid % NT_M;
  const int nt = bid / NT_M;
  const int slot0 = mt * 256;
  if (slot0 >= meta[16]) return;
  int e = 0;
#pragma unroll
  for (int i = 1; i < NEXP; ++i) e += (slot0 >= meta[8 + i]);
  const int tid = threadIdx.x;

  __shared__ u16 lds[2 * 32768];   // 2 x (A 32KB + B 32KB)
  char* ldsB = (char*)lds;

  const u16* Be = B + (size_t)e * 2048 * KT;
  const int* toklist = meta + META_TOK;

  // staging sources: 4 A-chunks + 4 B-chunks of 16B per thread.
  // dest linear L -> subtile S=L>>10, o=L&1023 ^ swizzle; row r=(S>>1)*16+(o>>6),
  // col byte cb=(S&1)*64+(o&63).
  const u16* asrc[4];
  const u16* bsrc[4];
#pragma unroll
  for (int j = 0; j < 4; ++j) {
    const int L = j * 8192 + tid * 16;
    const int S = L >> 10;
    int o = L & 1023;
    o ^= ((o >> 8) & 3) << 4;
    const int r = (S >> 1) * 16 + (o >> 6);
    const int cb = (S & 1) * 64 + (o & 63);
    const int arow = GATHER ? toklist[slot0 + r] : (slot0 + r);
    asrc[j] = A + (size_t)arow * KT + (cb >> 1);
    int brow;
    if (GUP) {
      const int g = r >> 6, j6 = r & 63;
      brow = nt * 128 + g * 32 + (j6 & 31) + ((j6 >> 5) << 10);  // gate | up+1024
    } else {
      brow = nt * 256 + r;
    }
    bsrc[j] = Be + (size_t)brow * KT + (cb >> 1);
  }

#define STAGE(kt_, c_)                                                                \
  do {                                                                                \
    char* dA_ = ldsB + (c_) * 65536;                                                  \
    char* dB_ = dA_ + 32768;                                                          \
    _Pragma("unroll") for (int j = 0; j < 4; ++j)                                     \
        __builtin_amdgcn_global_load_lds(                                             \
            (const __attribute__((address_space(1))) void*)(asrc[j] + (kt_) * 64),    \
            (__attribute__((address_space(3))) void*)(dA_ + j * 8192 + tid * 16),     \
            16, 0, 0);                                                                \
    _Pragma("unroll") for (int j = 0; j < 4; ++j)                                     \
        __builtin_amdgcn_global_load_lds(                                             \
            (const __attribute__((address_space(1))) void*)(bsrc[j] + (kt_) * 64),    \
            (__attribute__((address_space(3))) void*)(dB_ + j * 8192 + tid * 16),     \
            16, 0, 0);                                                                \
  } while (0)

  const int lane = tid & 63;
  const int wid = tid >> 6;
  const int wm = (wid >> 2) * 128;   // 2 M-groups of 128
  const int wn = (wid & 3) * 64;     // 4 N-groups of 64
  const int fr = lane & 15;
  const int qq = lane >> 4;
  const int swz = (qq * 16) ^ (((fr >> 2) & 3) << 4);

  int aoff[2][4][2], boff[4][2];
#pragma unroll
  for (int mh = 0; mh < 2; ++mh)
#pragma unroll
    for (int mf = 0; mf < 4; ++mf)
#pragma unroll
      for (int ks = 0; ks < 2; ++ks)
        aoff[mh][mf][ks] = ((wm + mh * 64 + mf * 16) >> 4) * 2048 + ks * 1024 + fr * 64 + swz;
#pragma unroll
  for (int nf = 0; nf < 4; ++nf)
#pragma unroll
    for (int ks = 0; ks < 2; ++ks)
      boff[nf][ks] = 32768 + ((wn + nf * 16) >> 4) * 2048 + ks * 1024 + fr * 64 + swz;

  f32x4 acc[8][4];
#pragma unroll
  for (int m = 0; m < 8; ++m)
#pragma unroll
    for (int n = 0; n < 4; ++n) acc[m][n] = (f32x4)0.0f;

#define COMPUTE(c_)                                                                   \
  do {                                                                                \
    const char* bb_ = ldsB + (c_) * 65536;                                            \
    bf16x8 bfr_[4][2];                                                                \
    _Pragma("unroll") for (int nf = 0; nf < 4; ++nf)                                  \
        _Pragma("unroll") for (int ks = 0; ks < 2; ++ks)                              \
            bfr_[nf][ks] = *(const bf16x8*)(bb_ + boff[nf][ks]);                      \
    _Pragma("unroll") for (int mh = 0; mh < 2; ++mh) {                                \
      bf16x8 af_[4][2];                                                               \
      _Pragma("unroll") for (int mf = 0; mf < 4; ++mf)                                \
          _Pragma("unroll") for (int ks = 0; ks < 2; ++ks)                            \
              af_[mf][ks] = *(const bf16x8*)(bb_ + aoff[mh][mf][ks]);                 \
      __builtin_amdgcn_s_setprio(1);                                                  \
      _Pragma("unroll") for (int mf = 0; mf < 4; ++mf)                                \
          _Pragma("unroll") for (int nf = 0; nf < 4; ++nf)                            \
              _Pragma("unroll") for (int ks = 0; ks < 2; ++ks)                        \
                  acc[mh * 4 + mf][nf] = __builtin_amdgcn_mfma_f32_16x16x32_bf16(     \
                      af_[mf][ks], bfr_[nf][ks], acc[mh * 4 + mf][nf], 0, 0, 0);      \
      __builtin_amdgcn_s_setprio(0);                                                  \
    }                                                                                 \
  } while (0)

  STAGE(0, 0);
#pragma unroll 1
  for (int kt = 0; kt < NT; kt += 2) {
    asm volatile("s_waitcnt vmcnt(0)" ::: "memory");
    __builtin_amdgcn_s_barrier();
    __builtin_amdgcn_sched_barrier(0);
    if (kt + 1 < NT) STAGE(kt + 1, 1);
    COMPUTE(0);
    asm volatile("s_waitcnt vmcnt(0)" ::: "memory");
    __builtin_amdgcn_s_barrier();
    __builtin_amdgcn_sched_barrier(0);
    if (kt + 2 < NT) STAGE(kt + 2, 0);
    COMPUTE(1);
  }
#undef STAGE
#undef COMPUTE

  // epilogue: C/D layout col=lane&15, row=(lane>>4)*4+j  [m89-verified]
  if (GUP) {
    // h[row, nt*128 + g*32 + n*16 + fr] = silu(acc[m][n]) * acc[m][n+2], n in {0,1}
    const int g = wid & 3;
#pragma unroll
    for (int mi = 0; mi < 8; ++mi)
#pragma unroll
      for (int n = 0; n < 2; ++n)
#pragma unroll
        for (int jj = 0; jj < 4; ++jj) {
          const float gv = acc[mi][n][jj];
          const float uv = acc[mi][n + 2][jj];
          const float hv = gv / (1.0f + __expf(-gv)) * uv;
          const int row = slot0 + wm + mi * 16 + qq * 4 + jj;
          Cout[(size_t)row * OSTR + nt * 128 + g * 32 + n * 16 + fr] = f2bf(hv);
        }
  } else {
#pragma unroll
    for (int mi = 0; mi < 8; ++mi)
#pragma unroll
      for (int n = 0; n < 4; ++n)
#pragma unroll
        for (int jj = 0; jj < 4; ++jj) {
          const int row = slot0 + wm + mi * 16 + qq * 4 + jj;
          const int col = nt * 256 + wn + n * 16 + fr;
          Cout[(size_t)row * OSTR + col] = f2bf(acc[mi][n][jj]);
        }
  }
}

// ---------------- combine ----------------
__global__ void combine_k(const u16* __restrict__ yp, const float* __restrict__ ew,
                          const int* __restrict__ meta, float* __restrict__ out) {
  const int idx = blockIdx.x * 256 + threadIdx.x;
  const int t = idx >> 8;
  const int pos = (idx & 255) * 8;
  const int* slot_of = meta + META_SLOTOF;
  const int s0 = slot_of[t * 2];
  const int s1 = slot_of[t * 2 + 1];
  const float w0 = ew[t * 2];
  const float w1 = ew[t * 2 + 1];
  const u16x8 v0 = *(const u16x8*)(yp + (size_t)s0 * 2048 + pos);
  const u16x8 v1 = *(const u16x8*)(yp + (size_t)s1 * 2048 + pos);
  float* dst = out + (size_t)t * 2048 + pos;
  float4 o0, o1;
  o0.x = w0 * bf2f(v0[0]) + w1 * bf2f(v1[0]);
  o0.y = w0 * bf2f(v0[1]) + w1 * bf2f(v1[1]);
  o0.z = w0 * bf2f(v0[2]) + w1 * bf2f(v1[2]);
  o0.w = w0 * bf2f(v0[3]) + w1 * bf2f(v1[3]);
  o1.x = w0 * bf2f(v0[4]) + w1 * bf2f(v1[4]);
  o1.y = w0 * bf2f(v0[5]) + w1 * bf2f(v1[5]);
  o1.z = w0 * bf2f(v0[6]) + w1 * bf2f(v1[6]);
  o1.w = w0 * bf2f(v0[7]) + w1 * bf2f(v1[7]);
  *(float4*)dst = o0;
  *(float4*)(dst + 4) = o1;
}

// ---------------- launch ----------------
extern "C" void kernel_launch(void* const* d_in, const int* in_sizes, int n_in,
                              void* d_out, int out_size, void* d_ws, size_t ws_size,
                              hipStream_t stream) {
  const float* x    = (const float*)d_in[0];
  const int*   w1   = (const int*)d_in[1];
  const float* w1s  = (const float*)d_in[2];
  const int*   w2   = (const int*)d_in[3];
  const float* w2s  = (const float*)d_in[4];
  const float* ew   = (const float*)d_in[5];
  const int*   eidx = (const int*)d_in[6];
  float* out = (float*)d_out;

  char* ws = (char*)d_ws;
  // ws layout (bytes); yp reuses W1b's region (dead after GEMM1)
  const size_t OFF_W1B  = 0;           // 8*2048*2048*2 = 67,108,864  (also yp: 10240*2048*2 = 41,943,040)
  const size_t OFF_W2B  = 67108864;    // 8*2048*1024*2 = 33,554,432
  const size_t OFF_XB   = 100663296;   // 4096*2048*2   = 16,777,216
  const size_t OFF_H    = 117440512;   // 10240*1024*2  = 20,971,520
  const size_t OFF_META = 138412032;   // 18464*4       = 73,856
  const size_t NEED     = 138485888;
  if (ws_size < NEED) return;

  u16* W1b  = (u16*)(ws + OFF_W1B);
  u16* yp   = (u16*)(ws + OFF_W1B);
  u16* W2b  = (u16*)(ws + OFF_W2B);
  u16* xb   = (u16*)(ws + OFF_XB);
  u16* hbuf = (u16*)(ws + OFF_H);
  int* meta = (int*)(ws + OFF_META);

  router_count<<<1, 256, 0, stream>>>(eidx, meta);
  toklist_init<<<SLOT_CAP / 256, 256, 0, stream>>>(meta);
  router_assign<<<T_TOK / 256, 256, 0, stream>>>(eidx, meta);

  cast_x_k<<<(T_TOK * HID) / (256 * 8), 256, 0, stream>>>(x, xb);
  dequant_k<256><<<16384 * 256 / 256, 256, 0, stream>>>(w1, w1s, W1b);
  dequant_k<128><<<16384 * 128 / 256, 256, 0, stream>>>(w2, w2s, W2b);

  // GEMM1 (+fused silu): hbuf[slot, 0..1024) ; grid bid = nt*40+mt, 8 n-tiles
  gemm256<2048, true, true><<<NT_M * 8, 512, 0, stream>>>(xb, W1b, hbuf, meta);
  // GEMM2: yp[slot, 0..2048) = h . W2^T  (K=1024); yp overlays W1b region
  gemm256<1024, false, false><<<NT_M * 8, 512, 0, stream>>>(hbuf, W2b, yp, meta);

  combine_k<<<(T_TOK * HID) / (256 * 8), 256, 0, stream>>>(yp, ew, meta, out);
}